// Round 4
// baseline (547.886 us; speedup 1.0000x reference)
//
#include <hip/hip_runtime.h>
#include <cstddef>
#include <cstdint>

// Problem: B=2, S=2048, E=1024, H=16, D=64.  Softmax over HEADS (ref quirk).
#define BATCH 2
#define S_LEN 2048
#define E_DIM 1024
#define NH    16
#define HD    64
#define M_ROWS (BATCH * S_LEN)   // 4096

// fold softmax scale into Q at projection time: 1/sqrt(64) * log2(e)
#define QSCALE 0.18033688011112042f

typedef unsigned short u16;
typedef short     bf16x8 __attribute__((ext_vector_type(8)));
typedef _Float16  f16x8  __attribute__((ext_vector_type(8)));
typedef __fp16    h16x2  __attribute__((ext_vector_type(2)));   // cvt_pkrtz return type
typedef float     f32x4  __attribute__((ext_vector_type(4)));

__device__ __forceinline__ u16 f2bf(float f) {
    union { float f; unsigned u; } v; v.f = f;
    unsigned r = v.u + 0x7fffu + ((v.u >> 16) & 1u);   // RNE
    return (u16)(r >> 16);
}
__device__ __forceinline__ float bf2f(u16 h) {
    union { unsigned u; float f; } v; v.u = ((unsigned)h) << 16;
    return v.f;
}

// async global->LDS DMA, 16 B per lane (global_load_lds_dwordx4).
__device__ __forceinline__ void load_lds16(const u16* g, u16* l) {
    __builtin_amdgcn_global_load_lds(
        (const __attribute__((address_space(1))) unsigned int*)g,
        (__attribute__((address_space(3))) unsigned int*)l, 16, 0, 0);
}

// ---------------------------------------------------------------------------
// fp32 -> bf16 bulk convert (n % 4 == 0)
// ---------------------------------------------------------------------------
__global__ void cvt_bf16(const float* __restrict__ in, u16* __restrict__ out, int n)
{
    int i = (blockIdx.x * 256 + threadIdx.x) * 4;
    if (i + 3 < n) {
        float4 v = *(const float4*)(in + i);
        u16 o[4] = { f2bf(v.x), f2bf(v.y), f2bf(v.z), f2bf(v.w) };
        *(uint2*)(out + i) = *(const uint2*)o;
    }
}

// ---------------------------------------------------------------------------
// ctx = a + b  (bf16 in, fp32 add, bf16 out)
// ---------------------------------------------------------------------------
__global__ void combine_ctx(const u16* __restrict__ a, const u16* __restrict__ b,
                            u16* __restrict__ c, int n)
{
    int i = (blockIdx.x * 256 + threadIdx.x) * 4;
    if (i + 3 < n) {
        uint2 ua = *(const uint2*)(a + i);
        uint2 ub = *(const uint2*)(b + i);
        const u16* pa = (const u16*)&ua; const u16* pb = (const u16*)&ub;
        u16 o[4];
#pragma unroll
        for (int j = 0; j < 4; ++j) o[j] = f2bf(bf2f(pa[j]) + bf2f(pb[j]));
        *(uint2*)(c + i) = *(const uint2*)o;
    }
}

// ---------------------------------------------------------------------------
// Fused QKV projection GEMM (m97-style DMA staging).
//   seg 0 -> Q, bf16, PRE-SCALED by QSCALE (softmax scale folded in)
//   seg 1 -> K, bf16
//   seg 2 -> V, written TRANSPOSED Vt[b][e][s] in FP16 (PV runs fp16 MFMA)
// ---------------------------------------------------------------------------
__global__ __launch_bounds__(256)
void gemm_qkv(const u16* __restrict__ A, const u16* __restrict__ W3,
              const float* __restrict__ bq, const float* __restrict__ bk,
              const float* __restrict__ bv,
              u16* __restrict__ Qb, u16* __restrict__ Kb, u16* __restrict__ Vtb)
{
    __shared__ u16 Al[128 * 32];
    __shared__ u16 Bl[128 * 32];
    const int K = E_DIM;
    const int t = threadIdx.x;
    const int w = t >> 6, lane = t & 63;
    const int quad = lane >> 4, lm = lane & 15;
    const int wy = w >> 1, wx = w & 1;
    const int m0 = blockIdx.x * 128, n0 = blockIdx.y * 128;
    const int lrow  = lane >> 2;
    const int lcol8 = (lane & 3) * 8;

    f32x4 acc[4][4] = {};

    for (int kb = 0; kb < K; kb += 32) {
        __syncthreads();
#pragma unroll
        for (int i = 0; i < 2; ++i) {
            const int r0 = w * 32 + i * 16;
            load_lds16(A  + (size_t)(m0 + r0 + lrow) * K + kb + lcol8, &Al[r0 * 32]);
            load_lds16(W3 + (size_t)(n0 + r0 + lrow) * K + kb + lcol8, &Bl[r0 * 32]);
        }
        __syncthreads();

        bf16x8 af[4], bfr[4];
#pragma unroll
        for (int i = 0; i < 4; ++i)
            af[i] = *(const bf16x8*)(Al + (wy * 64 + i * 16 + lm) * 32 + quad * 8);
#pragma unroll
        for (int j = 0; j < 4; ++j)
            bfr[j] = *(const bf16x8*)(Bl + (wx * 64 + j * 16 + lm) * 32 + quad * 8);
#pragma unroll
        for (int i = 0; i < 4; ++i)
#pragma unroll
            for (int j = 0; j < 4; ++j)
                acc[i][j] = __builtin_amdgcn_mfma_f32_16x16x32_bf16(af[i], bfr[j], acc[i][j], 0, 0, 0);
    }

    const int seg = n0 >> 10;            // 0=Q, 1=K, 2=V
    const int nl0 = n0 & 1023;
    const float* bs = (seg == 0) ? bq : (seg == 1) ? bk : bv;

    if (seg < 2) {
        u16* dst = (seg == 0) ? Qb : Kb;
        const float scl = (seg == 0) ? QSCALE : 1.0f;
#pragma unroll
        for (int j = 0; j < 4; ++j) {
            const int n = nl0 + wx * 64 + j * 16 + lm;
            const float bias = bs[n];
#pragma unroll
            for (int i = 0; i < 4; ++i) {
                const int mrow = m0 + wy * 64 + i * 16 + quad * 4;
#pragma unroll
                for (int rg = 0; rg < 4; ++rg)
                    dst[(size_t)(mrow + rg) * E_DIM + n] = f2bf((acc[i][j][rg] + bias) * scl);
            }
        }
    } else {
        // V: fp16, transposed -> Vt[b][e][s]
#pragma unroll
        for (int j = 0; j < 4; ++j) {
            const int n = nl0 + wx * 64 + j * 16 + lm;
            const float bias = bs[n];
#pragma unroll
            for (int i = 0; i < 4; ++i) {
                const int mrow = m0 + wy * 64 + i * 16 + quad * 4;
                const int batch = mrow >> 11;
                const int sloc  = mrow & 2047;
                u16 o[4];
#pragma unroll
                for (int rg = 0; rg < 4; ++rg) {
                    union { _Float16 h; u16 u; } cv;
                    cv.h = (_Float16)(acc[i][j][rg] + bias);
                    o[rg] = cv.u;
                }
                *(uint2*)&Vtb[(size_t)batch * E_DIM * S_LEN + (size_t)n * S_LEN + sloc]
                    = *(const uint2*)o;
            }
        }
    }
}

// ---------------------------------------------------------------------------
// Output projection GEMM — unchanged.
// ---------------------------------------------------------------------------
__global__ __launch_bounds__(256)
void gemm_wo(const u16* __restrict__ A, const u16* __restrict__ B,
             const float* __restrict__ bias, float* __restrict__ C)
{
    __shared__ u16 Al[128 * 32];
    __shared__ u16 Bl[128 * 32];
    const int K = E_DIM, N = E_DIM;
    const int t = threadIdx.x;
    const int w = t >> 6, lane = t & 63;
    const int quad = lane >> 4, lm = lane & 15;
    const int wy = w >> 1, wx = w & 1;
    const int m0 = blockIdx.x * 128, n0 = blockIdx.y * 128;
    const int lrow  = lane >> 2;
    const int lcol8 = (lane & 3) * 8;

    f32x4 acc[4][4] = {};

    for (int kb = 0; kb < K; kb += 32) {
        __syncthreads();
#pragma unroll
        for (int i = 0; i < 2; ++i) {
            const int r0 = w * 32 + i * 16;
            load_lds16(A + (size_t)(m0 + r0 + lrow) * K + kb + lcol8, &Al[r0 * 32]);
            load_lds16(B + (size_t)(n0 + r0 + lrow) * K + kb + lcol8, &Bl[r0 * 32]);
        }
        __syncthreads();

        bf16x8 af[4], bfr[4];
#pragma unroll
        for (int i = 0; i < 4; ++i)
            af[i] = *(const bf16x8*)(Al + (wy * 64 + i * 16 + lm) * 32 + quad * 8);
#pragma unroll
        for (int j = 0; j < 4; ++j)
            bfr[j] = *(const bf16x8*)(Bl + (wx * 64 + j * 16 + lm) * 32 + quad * 8);
#pragma unroll
        for (int i = 0; i < 4; ++i)
#pragma unroll
            for (int j = 0; j < 4; ++j)
                acc[i][j] = __builtin_amdgcn_mfma_f32_16x16x32_bf16(af[i], bfr[j], acc[i][j], 0, 0, 0);
    }

#pragma unroll
    for (int j = 0; j < 4; ++j) {
        const int n = n0 + wx * 64 + j * 16 + lm;
        const float bs = bias[n];
#pragma unroll
        for (int i = 0; i < 4; ++i) {
            const int mrow = m0 + wy * 64 + i * 16 + quad * 4;
#pragma unroll
            for (int rg = 0; rg < 4; ++rg)
                C[(size_t)(mrow + rg) * N + n] = acc[i][j][rg] + bs;
        }
    }
}

// ---------------------------------------------------------------------------
// attn_v6 = attn_v5 + (1) XCD-aware block decode, (2) K register ping-pong
// prefetch, (3) B1 barrier removed (2 barriers/iter; safe because the
// lgkmcnt(0) drain before each barrier retires all LDS reads wave-locally,
// and the barrier makes that global).
//
// One iteration (32 k-values), kcur prefetched last iter:
//   QK^T from kcur regs -> pack S4 (b128) -> issue V[c] + K[c+1] loads
//   -> lgkm drain -> B2 -> register softmax (S4 b128 reads, exp2, pkrtz)
//   -> P5 writes -> lgkm drain -> B3 -> PV (P5 b128 reads, fp16 MFMA).
// ---------------------------------------------------------------------------
__device__ __forceinline__ void attn_iter(
    const u16* __restrict__ K, const u16* __restrict__ Vt,
    size_t kmat, size_t vtb, int k0, int kn,
    int w, int quad, int lm, int sq, int sj,
    float* S4, u16* P5,
    const bf16x8 (&qf)[4][2],
    bf16x8 (&kcur)[4][2][2], bf16x8 (&knxt)[4][2][2],
    f32x4 (&oacc)[4][4])
{
    // ---- swapped QK^T from prefetched K regs: S[k][q], 4 heads ----
    f32x4 sacc[4][2];
#pragma unroll
    for (int h2 = 0; h2 < 4; ++h2)
#pragma unroll
        for (int kt = 0; kt < 2; ++kt) {
            f32x4 sf = {};
            sf = __builtin_amdgcn_mfma_f32_16x16x32_bf16(kcur[h2][kt][0], qf[h2][0], sf, 0, 0, 0);
            sf = __builtin_amdgcn_mfma_f32_16x16x32_bf16(kcur[h2][kt][1], qf[h2][1], sf, 0, 0, 0);
            sacc[h2][kt] = sf;
        }

    // ---- pack 4 heads per (k,q) slot -> one b128 store each ----
    // (safe without a preceding barrier: all S4 reads of the previous
    //  iteration were drained before B3 of that iteration)
#pragma unroll
    for (int kt = 0; kt < 2; ++kt)
#pragma unroll
        for (int rg = 0; rg < 4; ++rg) {
            f32x4 hv = { sacc[0][kt][rg], sacc[1][kt][rg],
                         sacc[2][kt][rg], sacc[3][kt][rg] };
            const int kl = kt * 16 + quad * 4 + rg;
            *(f32x4*)(S4 + (size_t)(kl * 16 + lm) * 20 + w * 4) = hv;
        }

    // ---- V[c] + K[c+1] prefetch; latency hides under softmax/PV ----
    f16x8 vf[4][4];
#pragma unroll
    for (int h2 = 0; h2 < 4; ++h2)
#pragma unroll
        for (int dt = 0; dt < 4; ++dt)
            vf[h2][dt] = *(const f16x8*)(Vt + vtb
                         + (size_t)((w * 4 + h2) * 64 + dt * 16 + lm) * S_LEN
                         + k0 + quad * 8);
#pragma unroll
    for (int h2 = 0; h2 < 4; ++h2)
#pragma unroll
        for (int kt = 0; kt < 2; ++kt)
#pragma unroll
            for (int hf = 0; hf < 2; ++hf)
                knxt[h2][kt][hf] = *(const bf16x8*)(K + kmat
                                   + (size_t)(kn + kt * 16 + lm) * E_DIM
                                   + (w * 4 + h2) * 64 + hf * 32 + quad * 8);

    asm volatile("s_waitcnt lgkmcnt(0)" ::: "memory");
    __builtin_amdgcn_s_barrier();   // B2: S4 visible everywhere

    // ---- register softmax over heads: 2 (k,q) slots per thread ----
    float pv[2][16];
#pragma unroll
    for (int ks = 0; ks < 2; ++ks) {
        const float* base = S4 + (size_t)((2 * sj + ks) * 16 + sq) * 20;
        f32x4 r0 = *(const f32x4*)(base);
        f32x4 r1 = *(const f32x4*)(base + 4);
        f32x4 r2 = *(const f32x4*)(base + 8);
        f32x4 r3 = *(const f32x4*)(base + 12);
        float s[16];
#pragma unroll
        for (int z = 0; z < 4; ++z) {
            s[z] = r0[z]; s[4 + z] = r1[z]; s[8 + z] = r2[z]; s[12 + z] = r3[z];
        }
        float m = s[0];
#pragma unroll
        for (int h = 1; h < 16; ++h) m = fmaxf(m, s[h]);
        float sum = 0.f;
#pragma unroll
        for (int h = 0; h < 16; ++h) {
            const float e = __builtin_amdgcn_exp2f(s[h] - m);  // scale folded into Q
            pv[ks][h] = e; sum += e;
        }
        const float inv = __builtin_amdgcn_rcpf(sum);
#pragma unroll
        for (int h = 0; h < 16; ++h) pv[ks][h] *= inv;
    }
    // pack fp16 pairs (k=2sj, 2sj+1) -> one u32 store per head
#pragma unroll
    for (int h = 0; h < 16; ++h) {
        union { h16x2 v; unsigned u; } cv;
        cv.v = __builtin_amdgcn_cvt_pkrtz(pv[0][h], pv[1][h]);
        *(unsigned*)(P5 + (size_t)h * 640 + sq * 40 + 2 * sj) = cv.u;
    }

    asm volatile("s_waitcnt lgkmcnt(0)" ::: "memory");
    __builtin_amdgcn_s_barrier();   // B3: P5 visible; all S4/P5 reads retired

    // ---- PV: fp16 MFMA, P A-frag one b128 per head, V from regs ----
#pragma unroll
    for (int h2 = 0; h2 < 4; ++h2) {
        f16x8 pa = *(const f16x8*)(P5 + (size_t)(w * 4 + h2) * 640
                                   + lm * 40 + quad * 8);
#pragma unroll
        for (int dt = 0; dt < 4; ++dt)
            oacc[h2][dt] = __builtin_amdgcn_mfma_f32_16x16x32_f16(pa, vf[h2][dt],
                                                                  oacc[h2][dt], 0, 0, 0);
    }
}

__global__ __launch_bounds__(256, 2)
void attn_v6(const u16* __restrict__ Q, const u16* __restrict__ K,
             const u16* __restrict__ Vt, u16* __restrict__ ctxA,
             u16* __restrict__ ctxB)
{
    __shared__ __align__(16) u16 smem[30720];   // 61440 B
    float* S4 = (float*)smem;                   // [512 slots][20 f32]  40960 B
    u16*   P5 = smem + 20480;                   // [16h][16q][40 halves] 20480 B

    const int t     = threadIdx.x;
    const int w     = t >> 6, lane = t & 63;
    const int quad  = lane >> 4, lm = lane & 15;

    // XCD-aware decode (model: XCD = blockIdx % 8, round-robin dispatch).
    // Each (b,khalf) combo -> XCD pair {2c,2c+1}: its K-half (2MB) + V-half
    // (2MB) working set fits that XCD's 4MB L2.  Pure permutation of the
    // (b,khalf,qt) space — correctness never depends on the mapping.
    const int i     = blockIdx.x;
    const int xcd   = i & 7;
    const int slot  = i >> 3;            // 0..63
    const int combo = xcd >> 1;          // 0..3
    const int b     = combo >> 1;
    const int khalf = combo & 1;
    const int qt    = ((xcd & 1) << 6) | slot;   // 0..127
    const int q0    = qt * 16;

    const size_t qbase = ((size_t)b * S_LEN + q0) * E_DIM;
    const size_t kmat  = (size_t)b * S_LEN * E_DIM;
    const size_t vtb   = (size_t)b * E_DIM * S_LEN;

    // Q fragments (B-operand of swapped QK^T), loop-invariant
    bf16x8 qf[4][2];
#pragma unroll
    for (int h2 = 0; h2 < 4; ++h2)
#pragma unroll
        for (int hf = 0; hf < 2; ++hf)
            qf[h2][hf] = *(const bf16x8*)(Q + qbase + (size_t)lm * E_DIM
                                          + (w * 4 + h2) * 64 + hf * 32 + quad * 8);

    f32x4 oacc[4][4] = {};   // [h2][dtile]
    const int kbeg = khalf * (S_LEN / 2);
    const int sq = t & 15, sj = t >> 4;   // softmax slot: q=sq, k in {2sj, 2sj+1}

    // preload K chunk 0 into kA
    bf16x8 kA[4][2][2], kB[4][2][2];
#pragma unroll
    for (int h2 = 0; h2 < 4; ++h2)
#pragma unroll
        for (int kt = 0; kt < 2; ++kt)
#pragma unroll
            for (int hf = 0; hf < 2; ++hf)
                kA[h2][kt][hf] = *(const bf16x8*)(K + kmat
                                 + (size_t)(kbeg + kt * 16 + lm) * E_DIM
                                 + (w * 4 + h2) * 64 + hf * 32 + quad * 8);

    // 32 chunks of 32 k-values, 2x unrolled ping-pong (kA/kB)
    for (int cc = 0; cc < 16; ++cc) {
        const int c0 = cc * 2;
        const int k0 = kbeg + c0 * 32;
        const int k1 = k0 + 32;
        const int k2 = (c0 + 1 == 31) ? k1 : k1 + 32;  // clamp last prefetch (valid addr)
        attn_iter(K, Vt, kmat, vtb, k0, k1, w, quad, lm, sq, sj,
                  S4, P5, qf, kA, kB, oacc);
        attn_iter(K, Vt, kmat, vtb, k1, k2, w, quad, lm, sq, sj,
                  S4, P5, qf, kB, kA, oacc);
    }

    __syncthreads();
    u16* Ol = smem;          // [16 q][1024 e] = 32768 B <= 61440 B
#pragma unroll
    for (int h2 = 0; h2 < 4; ++h2) {
        const int h = w * 4 + h2;
#pragma unroll
        for (int dt = 0; dt < 4; ++dt)
#pragma unroll
            for (int rg = 0; rg < 4; ++rg)
                Ol[(quad * 4 + rg) * 1024 + h * 64 + dt * 16 + lm] = f2bf(oacc[h2][dt][rg]);
    }
    __syncthreads();
    u16* dst = khalf ? ctxB : ctxA;
#pragma unroll
    for (int i2 = 0; i2 < 8; ++i2) {
        const int unit = i2 * 256 + t;
        const int r = unit >> 7, cu = unit & 127;
        *(bf16x8*)(dst + ((size_t)b * S_LEN + q0 + r) * E_DIM + cu * 8) =
            *(const bf16x8*)(Ol + r * 1024 + cu * 8);
    }
}

// ---------------------------------------------------------------------------
extern "C" void kernel_launch(void* const* d_in, const int* in_sizes, int n_in,
                              void* d_out, int out_size, void* d_ws, size_t ws_size,
                              hipStream_t stream)
{
    const float* x  = (const float*)d_in[0];
    const float* Wq = (const float*)d_in[1];
    const float* bq = (const float*)d_in[2];
    const float* Wk = (const float*)d_in[3];
    const float* bk = (const float*)d_in[4];
    const float* Wv = (const float*)d_in[5];
    const float* bv = (const float*)d_in[6];
    const float* Wo = (const float*)d_in[7];
    const float* bo = (const float*)d_in[8];
    float* out = (float*)d_out;

    // bf16/fp16 workspace (u16 elems), 56 MB:
    const size_t MAT = (size_t)M_ROWS * E_DIM;   // 4M elems
    const size_t WSZ = (size_t)E_DIM * E_DIM;    // 1M elems
    u16* xb   = (u16*)d_ws;          // x; later combined ctx
    u16* W3   = xb   + MAT;          // Wq|Wk|Wv concat [3072][1024]
    u16* Wob  = W3   + 3 * WSZ;
    u16* Qb   = Wob  + WSZ;
    u16* Kb   = Qb   + MAT;
    u16* Vtb  = Kb   + MAT;          // V transposed [b][e][s], FP16
    u16* ctxA = Vtb  + MAT;
    u16* ctxB = ctxA + MAT;

    // 1) convert inputs to bf16 (weights into concat buffer)
    cvt_bf16<<<(int)(MAT / 1024), 256, 0, stream>>>(x,  xb, (int)MAT);
    cvt_bf16<<<(int)(WSZ / 1024), 256, 0, stream>>>(Wq, W3,           (int)WSZ);
    cvt_bf16<<<(int)(WSZ / 1024), 256, 0, stream>>>(Wk, W3 + WSZ,     (int)WSZ);
    cvt_bf16<<<(int)(WSZ / 1024), 256, 0, stream>>>(Wv, W3 + 2 * WSZ, (int)WSZ);
    cvt_bf16<<<(int)(WSZ / 1024), 256, 0, stream>>>(Wo, Wob,          (int)WSZ);

    // 2) fused QKV projection (Q pre-scaled, V fp16-transposed)
    dim3 qkvgrid(M_ROWS / 128, 3 * E_DIM / 128);   // 32 x 24 = 768 blocks
    gemm_qkv<<<qkvgrid, 256, 0, stream>>>(xb, W3, bq, bk, bv, Qb, Kb, Vtb);

    // 3) fused MFMA attention (softmax over heads), KSPLIT=2, XCD-clustered
    attn_v6<<<BATCH * 128 * 2, 256, 0, stream>>>(Qb, Kb, Vtb, ctxA, ctxB);

    // 4) combine k-halves into xb (x is dead)
    combine_ctx<<<(int)(MAT / 1024), 256, 0, stream>>>(ctxA, ctxB, xb, (int)MAT);

    // 5) output projection (fp32 out)
    dim3 ogrid(M_ROWS / 128, E_DIM / 128);         // 32 x 8
    gemm_wo<<<ogrid, 256, 0, stream>>>(xb, Wob, bo, out);
}

// Round 5
// 403.740 us; speedup vs baseline: 1.3570x; 1.3570x over previous
//
#include <hip/hip_runtime.h>
#include <cstddef>
#include <cstdint>

// Problem: B=2, S=2048, E=1024, H=16, D=64.  Softmax over HEADS (ref quirk).
#define BATCH 2
#define S_LEN 2048
#define E_DIM 1024
#define NH    16
#define HD    64
#define M_ROWS (BATCH * S_LEN)   // 4096

// fold softmax scale into Q at projection time: 1/sqrt(64) * log2(e)
#define QSCALE 0.18033688011112042f

typedef unsigned short u16;
typedef short     bf16x8 __attribute__((ext_vector_type(8)));
typedef _Float16  f16x8  __attribute__((ext_vector_type(8)));
typedef __fp16    h16x2  __attribute__((ext_vector_type(2)));   // cvt_pkrtz return type
typedef float     f32x4  __attribute__((ext_vector_type(4)));

__device__ __forceinline__ u16 f2bf(float f) {
    union { float f; unsigned u; } v; v.f = f;
    unsigned r = v.u + 0x7fffu + ((v.u >> 16) & 1u);   // RNE
    return (u16)(r >> 16);
}
__device__ __forceinline__ float bf2f(u16 h) {
    union { unsigned u; float f; } v; v.u = ((unsigned)h) << 16;
    return v.f;
}

// async global->LDS DMA, 16 B per lane (global_load_lds_dwordx4).
__device__ __forceinline__ void load_lds16(const u16* g, u16* l) {
    __builtin_amdgcn_global_load_lds(
        (const __attribute__((address_space(1))) unsigned int*)g,
        (__attribute__((address_space(3))) unsigned int*)l, 16, 0, 0);
}

// ---------------------------------------------------------------------------
// fp32 -> bf16 bulk convert (n % 4 == 0)
// ---------------------------------------------------------------------------
__global__ void cvt_bf16(const float* __restrict__ in, u16* __restrict__ out, int n)
{
    int i = (blockIdx.x * 256 + threadIdx.x) * 4;
    if (i + 3 < n) {
        float4 v = *(const float4*)(in + i);
        u16 o[4] = { f2bf(v.x), f2bf(v.y), f2bf(v.z), f2bf(v.w) };
        *(uint2*)(out + i) = *(const uint2*)o;
    }
}

// ---------------------------------------------------------------------------
// ctx = a + b  (bf16 in, fp32 add, bf16 out)
// ---------------------------------------------------------------------------
__global__ void combine_ctx(const u16* __restrict__ a, const u16* __restrict__ b,
                            u16* __restrict__ c, int n)
{
    int i = (blockIdx.x * 256 + threadIdx.x) * 4;
    if (i + 3 < n) {
        uint2 ua = *(const uint2*)(a + i);
        uint2 ub = *(const uint2*)(b + i);
        const u16* pa = (const u16*)&ua; const u16* pb = (const u16*)&ub;
        u16 o[4];
#pragma unroll
        for (int j = 0; j < 4; ++j) o[j] = f2bf(bf2f(pa[j]) + bf2f(pb[j]));
        *(uint2*)(c + i) = *(const uint2*)o;
    }
}

// ---------------------------------------------------------------------------
// Fused QKV projection GEMM (m97-style DMA staging).
//   seg 0 -> Q, bf16, PRE-SCALED by QSCALE (softmax scale folded in)
//   seg 1 -> K, bf16
//   seg 2 -> V, written TRANSPOSED Vt[b][e][s] in FP16 (PV runs fp16 MFMA)
// ---------------------------------------------------------------------------
__global__ __launch_bounds__(256)
void gemm_qkv(const u16* __restrict__ A, const u16* __restrict__ W3,
              const float* __restrict__ bq, const float* __restrict__ bk,
              const float* __restrict__ bv,
              u16* __restrict__ Qb, u16* __restrict__ Kb, u16* __restrict__ Vtb)
{
    __shared__ u16 Al[128 * 32];
    __shared__ u16 Bl[128 * 32];
    const int K = E_DIM;
    const int t = threadIdx.x;
    const int w = t >> 6, lane = t & 63;
    const int quad = lane >> 4, lm = lane & 15;
    const int wy = w >> 1, wx = w & 1;
    const int m0 = blockIdx.x * 128, n0 = blockIdx.y * 128;
    const int lrow  = lane >> 2;
    const int lcol8 = (lane & 3) * 8;

    f32x4 acc[4][4] = {};

    for (int kb = 0; kb < K; kb += 32) {
        __syncthreads();
#pragma unroll
        for (int i = 0; i < 2; ++i) {
            const int r0 = w * 32 + i * 16;
            load_lds16(A  + (size_t)(m0 + r0 + lrow) * K + kb + lcol8, &Al[r0 * 32]);
            load_lds16(W3 + (size_t)(n0 + r0 + lrow) * K + kb + lcol8, &Bl[r0 * 32]);
        }
        __syncthreads();

        bf16x8 af[4], bfr[4];
#pragma unroll
        for (int i = 0; i < 4; ++i)
            af[i] = *(const bf16x8*)(Al + (wy * 64 + i * 16 + lm) * 32 + quad * 8);
#pragma unroll
        for (int j = 0; j < 4; ++j)
            bfr[j] = *(const bf16x8*)(Bl + (wx * 64 + j * 16 + lm) * 32 + quad * 8);
#pragma unroll
        for (int i = 0; i < 4; ++i)
#pragma unroll
            for (int j = 0; j < 4; ++j)
                acc[i][j] = __builtin_amdgcn_mfma_f32_16x16x32_bf16(af[i], bfr[j], acc[i][j], 0, 0, 0);
    }

    const int seg = n0 >> 10;            // 0=Q, 1=K, 2=V
    const int nl0 = n0 & 1023;
    const float* bs = (seg == 0) ? bq : (seg == 1) ? bk : bv;

    if (seg < 2) {
        u16* dst = (seg == 0) ? Qb : Kb;
        const float scl = (seg == 0) ? QSCALE : 1.0f;
#pragma unroll
        for (int j = 0; j < 4; ++j) {
            const int n = nl0 + wx * 64 + j * 16 + lm;
            const float bias = bs[n];
#pragma unroll
            for (int i = 0; i < 4; ++i) {
                const int mrow = m0 + wy * 64 + i * 16 + quad * 4;
#pragma unroll
                for (int rg = 0; rg < 4; ++rg)
                    dst[(size_t)(mrow + rg) * E_DIM + n] = f2bf((acc[i][j][rg] + bias) * scl);
            }
        }
    } else {
        // V: fp16, transposed -> Vt[b][e][s]
#pragma unroll
        for (int j = 0; j < 4; ++j) {
            const int n = nl0 + wx * 64 + j * 16 + lm;
            const float bias = bs[n];
#pragma unroll
            for (int i = 0; i < 4; ++i) {
                const int mrow = m0 + wy * 64 + i * 16 + quad * 4;
                const int batch = mrow >> 11;
                const int sloc  = mrow & 2047;
                u16 o[4];
#pragma unroll
                for (int rg = 0; rg < 4; ++rg) {
                    union { _Float16 h; u16 u; } cv;
                    cv.h = (_Float16)(acc[i][j][rg] + bias);
                    o[rg] = cv.u;
                }
                *(uint2*)&Vtb[(size_t)batch * E_DIM * S_LEN + (size_t)n * S_LEN + sloc]
                    = *(const uint2*)o;
            }
        }
    }
}

// ---------------------------------------------------------------------------
// Output projection GEMM — unchanged.
// ---------------------------------------------------------------------------
__global__ __launch_bounds__(256)
void gemm_wo(const u16* __restrict__ A, const u16* __restrict__ B,
             const float* __restrict__ bias, float* __restrict__ C)
{
    __shared__ u16 Al[128 * 32];
    __shared__ u16 Bl[128 * 32];
    const int K = E_DIM, N = E_DIM;
    const int t = threadIdx.x;
    const int w = t >> 6, lane = t & 63;
    const int quad = lane >> 4, lm = lane & 15;
    const int wy = w >> 1, wx = w & 1;
    const int m0 = blockIdx.x * 128, n0 = blockIdx.y * 128;
    const int lrow  = lane >> 2;
    const int lcol8 = (lane & 3) * 8;

    f32x4 acc[4][4] = {};

    for (int kb = 0; kb < K; kb += 32) {
        __syncthreads();
#pragma unroll
        for (int i = 0; i < 2; ++i) {
            const int r0 = w * 32 + i * 16;
            load_lds16(A + (size_t)(m0 + r0 + lrow) * K + kb + lcol8, &Al[r0 * 32]);
            load_lds16(B + (size_t)(n0 + r0 + lrow) * K + kb + lcol8, &Bl[r0 * 32]);
        }
        __syncthreads();

        bf16x8 af[4], bfr[4];
#pragma unroll
        for (int i = 0; i < 4; ++i)
            af[i] = *(const bf16x8*)(Al + (wy * 64 + i * 16 + lm) * 32 + quad * 8);
#pragma unroll
        for (int j = 0; j < 4; ++j)
            bfr[j] = *(const bf16x8*)(Bl + (wx * 64 + j * 16 + lm) * 32 + quad * 8);
#pragma unroll
        for (int i = 0; i < 4; ++i)
#pragma unroll
            for (int j = 0; j < 4; ++j)
                acc[i][j] = __builtin_amdgcn_mfma_f32_16x16x32_bf16(af[i], bfr[j], acc[i][j], 0, 0, 0);
    }

#pragma unroll
    for (int j = 0; j < 4; ++j) {
        const int n = n0 + wx * 64 + j * 16 + lm;
        const float bs = bias[n];
#pragma unroll
        for (int i = 0; i < 4; ++i) {
            const int mrow = m0 + wy * 64 + i * 16 + quad * 4;
#pragma unroll
            for (int rg = 0; rg < 4; ++rg)
                C[(size_t)(mrow + rg) * N + n] = acc[i][j][rg] + bs;
        }
    }
}

// ---------------------------------------------------------------------------
// attn_v7 = attn_v5 (R3, 249 us) + ONLY two zero-register-pressure deltas:
//   (1) XCD-aware block decode: each (b,khalf) combo -> one XCD pair, so its
//       2MB K-half + 2MB V-half working set is L2-resident there.
//   (2) B1 barrier removed (2 barriers/iter).  Safe: every wave drains
//       lgkmcnt(0) before B2 and B3, so at each barrier ALL waves' S4/P5
//       LDS reads are retired; post-barrier writes cannot race them.
// NO K ping-pong (R4's scratch-spill source), NO helper function.
// ---------------------------------------------------------------------------
__global__ __launch_bounds__(256, 2)
void attn_v7(const u16* __restrict__ Q, const u16* __restrict__ K,
             const u16* __restrict__ Vt, u16* __restrict__ ctxA,
             u16* __restrict__ ctxB)
{
    __shared__ __align__(16) u16 smem[30720];   // 61440 B
    float* S4 = (float*)smem;                   // [512 slots][20 f32]  40960 B
    u16*   P5 = smem + 20480;                   // [16h][16q][40 halves] 20480 B

    const int t     = threadIdx.x;
    const int w     = t >> 6, lane = t & 63;
    const int quad  = lane >> 4, lm = lane & 15;

    // XCD-aware decode (model: XCD = blockIdx % 8, round-robin dispatch).
    // Pure permutation of (b,khalf,qt) — correctness independent of mapping.
    const int i     = blockIdx.x;
    const int xcd   = i & 7;
    const int slot  = i >> 3;            // 0..63
    const int combo = xcd >> 1;          // 0..3
    const int b     = combo >> 1;
    const int khalf = combo & 1;
    const int qt    = ((xcd & 1) << 6) | slot;   // 0..127
    const int q0    = qt * 16;

    const size_t qbase = ((size_t)b * S_LEN + q0) * E_DIM;
    const size_t kmat  = (size_t)b * S_LEN * E_DIM;
    const size_t vtb   = (size_t)b * E_DIM * S_LEN;

    // Q fragments (B-operand of swapped QK^T), loop-invariant
    bf16x8 qf[4][2];
#pragma unroll
    for (int h2 = 0; h2 < 4; ++h2)
#pragma unroll
        for (int hf = 0; hf < 2; ++hf)
            qf[h2][hf] = *(const bf16x8*)(Q + qbase + (size_t)lm * E_DIM
                                          + (w * 4 + h2) * 64 + hf * 32 + quad * 8);

    f32x4 oacc[4][4] = {};   // [h2][dtile]
    const int kbeg = khalf * (S_LEN / 2);
    const int sq = t & 15, sj = t >> 4;   // softmax slot: q=sq, k in {2sj, 2sj+1}

    for (int c = 0; c < (S_LEN / 2) / 32; ++c) {
        const int k0 = kbeg + c * 32;

        // ---- swapped QK^T: S[k][q] for this wave's 4 heads ----
        f32x4 sacc[4][2];
#pragma unroll
        for (int h2 = 0; h2 < 4; ++h2) {
            const int h = w * 4 + h2;
#pragma unroll
            for (int kt = 0; kt < 2; ++kt) {
                f32x4 sf = {};
#pragma unroll
                for (int hf = 0; hf < 2; ++hf) {
                    bf16x8 kf = *(const bf16x8*)(K + kmat
                                 + (size_t)(k0 + kt * 16 + lm) * E_DIM
                                 + h * 64 + hf * 32 + quad * 8);
                    sf = __builtin_amdgcn_mfma_f32_16x16x32_bf16(kf, qf[h2][hf], sf, 0, 0, 0);
                }
                sacc[h2][kt] = sf;
            }
        }

        // ---- pack 4 heads per (k,q) slot -> one b128 store each ----
        // (no barrier needed: all waves' S4 reads retired at prev B3)
#pragma unroll
        for (int kt = 0; kt < 2; ++kt)
#pragma unroll
            for (int rg = 0; rg < 4; ++rg) {
                f32x4 hv = { sacc[0][kt][rg], sacc[1][kt][rg],
                             sacc[2][kt][rg], sacc[3][kt][rg] };
                const int kl = kt * 16 + quad * 4 + rg;
                *(f32x4*)(S4 + (size_t)(kl * 16 + lm) * 20 + w * 4) = hv;
            }

        // V prefetch into regs; latency hides under softmax (vmcnt never drained)
        f16x8 vf[4][4];
#pragma unroll
        for (int h2 = 0; h2 < 4; ++h2)
#pragma unroll
            for (int dt = 0; dt < 4; ++dt)
                vf[h2][dt] = *(const f16x8*)(Vt + vtb
                             + (size_t)((w * 4 + h2) * 64 + dt * 16 + lm) * S_LEN
                             + k0 + quad * 8);

        asm volatile("s_waitcnt lgkmcnt(0)" ::: "memory");
        __builtin_amdgcn_s_barrier();   // B2: S4 visible everywhere

        // ---- register softmax over heads: 2 (k,q) slots per thread ----
        float pv[2][16];
#pragma unroll
        for (int ks = 0; ks < 2; ++ks) {
            const float* base = S4 + (size_t)((2 * sj + ks) * 16 + sq) * 20;
            f32x4 r0 = *(const f32x4*)(base);
            f32x4 r1 = *(const f32x4*)(base + 4);
            f32x4 r2 = *(const f32x4*)(base + 8);
            f32x4 r3 = *(const f32x4*)(base + 12);
            float s[16];
#pragma unroll
            for (int z = 0; z < 4; ++z) {
                s[z] = r0[z]; s[4 + z] = r1[z]; s[8 + z] = r2[z]; s[12 + z] = r3[z];
            }
            float m = s[0];
#pragma unroll
            for (int h = 1; h < 16; ++h) m = fmaxf(m, s[h]);
            float sum = 0.f;
#pragma unroll
            for (int h = 0; h < 16; ++h) {
                const float e = __builtin_amdgcn_exp2f(s[h] - m);  // scale folded into Q
                pv[ks][h] = e; sum += e;
            }
            const float inv = __builtin_amdgcn_rcpf(sum);
#pragma unroll
            for (int h = 0; h < 16; ++h) pv[ks][h] *= inv;
        }
        // pack fp16 pairs (k=2sj, 2sj+1) -> one u32 store per head
#pragma unroll
        for (int h = 0; h < 16; ++h) {
            union { h16x2 v; unsigned u; } cv;
            cv.v = __builtin_amdgcn_cvt_pkrtz(pv[0][h], pv[1][h]);
            *(unsigned*)(P5 + (size_t)h * 640 + sq * 40 + 2 * sj) = cv.u;
        }

        asm volatile("s_waitcnt lgkmcnt(0)" ::: "memory");
        __builtin_amdgcn_s_barrier();   // B3: P5 visible; all S4/P5 reads retired

        // ---- PV: fp16 MFMA, P A-frag one b128 per head, V from regs ----
#pragma unroll
        for (int h2 = 0; h2 < 4; ++h2) {
            f16x8 pa = *(const f16x8*)(P5 + (size_t)(w * 4 + h2) * 640
                                       + lm * 40 + quad * 8);
#pragma unroll
            for (int dt = 0; dt < 4; ++dt)
                oacc[h2][dt] = __builtin_amdgcn_mfma_f32_16x16x32_f16(pa, vf[h2][dt],
                                                                      oacc[h2][dt], 0, 0, 0);
        }
    }

    __syncthreads();
    u16* Ol = smem;          // [16 q][1024 e] = 32768 B <= 61440 B
#pragma unroll
    for (int h2 = 0; h2 < 4; ++h2) {
        const int h = w * 4 + h2;
#pragma unroll
        for (int dt = 0; dt < 4; ++dt)
#pragma unroll
            for (int rg = 0; rg < 4; ++rg)
                Ol[(quad * 4 + rg) * 1024 + h * 64 + dt * 16 + lm] = f2bf(oacc[h2][dt][rg]);
    }
    __syncthreads();
    u16* dst = khalf ? ctxB : ctxA;
#pragma unroll
    for (int i2 = 0; i2 < 8; ++i2) {
        const int unit = i2 * 256 + t;
        const int r = unit >> 7, cu = unit & 127;
        *(bf16x8*)(dst + ((size_t)b * S_LEN + q0 + r) * E_DIM + cu * 8) =
            *(const bf16x8*)(Ol + r * 1024 + cu * 8);
    }
}

// ---------------------------------------------------------------------------
extern "C" void kernel_launch(void* const* d_in, const int* in_sizes, int n_in,
                              void* d_out, int out_size, void* d_ws, size_t ws_size,
                              hipStream_t stream)
{
    const float* x  = (const float*)d_in[0];
    const float* Wq = (const float*)d_in[1];
    const float* bq = (const float*)d_in[2];
    const float* Wk = (const float*)d_in[3];
    const float* bk = (const float*)d_in[4];
    const float* Wv = (const float*)d_in[5];
    const float* bv = (const float*)d_in[6];
    const float* Wo = (const float*)d_in[7];
    const float* bo = (const float*)d_in[8];
    float* out = (float*)d_out;

    // bf16/fp16 workspace (u16 elems), 56 MB:
    const size_t MAT = (size_t)M_ROWS * E_DIM;   // 4M elems
    const size_t WSZ = (size_t)E_DIM * E_DIM;    // 1M elems
    u16* xb   = (u16*)d_ws;          // x; later combined ctx
    u16* W3   = xb   + MAT;          // Wq|Wk|Wv concat [3072][1024]
    u16* Wob  = W3   + 3 * WSZ;
    u16* Qb   = Wob  + WSZ;
    u16* Kb   = Qb   + MAT;
    u16* Vtb  = Kb   + MAT;          // V transposed [b][e][s], FP16
    u16* ctxA = Vtb  + MAT;
    u16* ctxB = ctxA + MAT;

    // 1) convert inputs to bf16 (weights into concat buffer)
    cvt_bf16<<<(int)(MAT / 1024), 256, 0, stream>>>(x,  xb, (int)MAT);
    cvt_bf16<<<(int)(WSZ / 1024), 256, 0, stream>>>(Wq, W3,           (int)WSZ);
    cvt_bf16<<<(int)(WSZ / 1024), 256, 0, stream>>>(Wk, W3 + WSZ,     (int)WSZ);
    cvt_bf16<<<(int)(WSZ / 1024), 256, 0, stream>>>(Wv, W3 + 2 * WSZ, (int)WSZ);
    cvt_bf16<<<(int)(WSZ / 1024), 256, 0, stream>>>(Wo, Wob,          (int)WSZ);

    // 2) fused QKV projection (Q pre-scaled, V fp16-transposed)
    dim3 qkvgrid(M_ROWS / 128, 3 * E_DIM / 128);   // 32 x 24 = 768 blocks
    gemm_qkv<<<qkvgrid, 256, 0, stream>>>(xb, W3, bq, bk, bv, Qb, Kb, Vtb);

    // 3) fused MFMA attention (softmax over heads), KSPLIT=2, XCD-clustered
    attn_v7<<<BATCH * 128 * 2, 256, 0, stream>>>(Qb, Kb, Vtb, ctxA, ctxB);

    // 4) combine k-halves into xb (x is dead)
    combine_ctx<<<(int)(MAT / 1024), 256, 0, stream>>>(ctxA, ctxB, xb, (int)MAT);

    // 5) output projection (fp32 out)
    dim3 ogrid(M_ROWS / 128, E_DIM / 128);         // 32 x 8
    gemm_wo<<<ogrid, 256, 0, stream>>>(xb, Wob, bo, out);
}